// Round 1
// baseline (572.214 us; speedup 1.0000x reference)
//
#include <hip/hip_runtime.h>
#include <math.h>

#define N_NODES 100000
#define N_EDGES 1600000
#define LN_EPS 1e-5f
#define NORM_EPS 1e-12f

// ---------------------------------------------------------------------------
// K1: h = x @ W^T + b  (N x 64), plus per-node attention scores
//     s_src[i][hd] = dot(h[i][hd], a[hd][0:8]) ; s_dst uses a[hd][8:16]
// Block: 256 threads = 4 waves; each wave computes 4 rows (16 rows/block).
// W transposed into LDS with stride 65 (conflict-free read AND write).
// ---------------------------------------------------------------------------
__global__ __launch_bounds__(256) void k_gemm(
    const float* __restrict__ x, const float* __restrict__ W,
    const float* __restrict__ b, const float* __restrict__ a,
    float* __restrict__ h, float* __restrict__ s_src, float* __restrict__ s_dst)
{
    __shared__ float WL[64 * 65];   // WL[k*65 + c] = W[c*64 + k]
    __shared__ float xs[16 * 64];
    const int tid  = threadIdx.x;
    const int lane = tid & 63;
    const int wv   = tid >> 6;

    for (int idx = tid; idx < 64 * 64; idx += 256) {
        int c = idx >> 6, k = idx & 63;
        WL[k * 65 + c] = W[idx];
    }
    const int row0 = blockIdx.x * 16;
    for (int idx = tid; idx < 16 * 64; idx += 256) {
        int r = row0 + (idx >> 6);
        xs[idx] = (r < N_NODES) ? x[(size_t)r * 64 + (idx & 63)] : 0.f;
    }
    __syncthreads();

    const float asrc = a[(lane >> 3) * 16 + (lane & 7)];
    const float adst = a[(lane >> 3) * 16 + 8 + (lane & 7)];
    const float bias = b[lane];

    float sum0 = 0.f, sum1 = 0.f, sum2 = 0.f, sum3 = 0.f;
    const int rbase = wv * 4;
    #pragma unroll
    for (int k = 0; k < 64; ++k) {
        float wk = WL[k * 65 + lane];           // 2 lanes/bank: free
        sum0 += xs[(rbase + 0) * 64 + k] * wk;  // broadcast: free
        sum1 += xs[(rbase + 1) * 64 + k] * wk;
        sum2 += xs[(rbase + 2) * 64 + k] * wk;
        sum3 += xs[(rbase + 3) * 64 + k] * wk;
    }
    float sums[4] = {sum0 + bias, sum1 + bias, sum2 + bias, sum3 + bias};
    #pragma unroll
    for (int j = 0; j < 4; ++j) {
        int r = row0 + rbase + j;
        if (r >= N_NODES) break;
        float v = sums[j];
        h[(size_t)r * 64 + lane] = v;
        // reduce within each head group of 8 lanes
        float p = v * asrc, q = v * adst;
        p += __shfl_xor(p, 1);  q += __shfl_xor(q, 1);
        p += __shfl_xor(p, 2);  q += __shfl_xor(q, 2);
        p += __shfl_xor(p, 4);  q += __shfl_xor(q, 4);
        if ((lane & 7) == 0) {
            s_src[r * 8 + (lane >> 3)] = p;
            s_dst[r * 8 + (lane >> 3)] = q;
        }
    }
}

// ---------------------------------------------------------------------------
// K2: per-edge attention + scatter.  One wave per edge; lane = dim (0..63),
// head = lane>>3.  Softmax over 8 heads via xor-shuffles 8/16/32: the
// butterfly set {lane ^ (b<<3)} covers each head exactly once -> exact sum.
// ---------------------------------------------------------------------------
__global__ __launch_bounds__(256) void k_edge(
    const int* __restrict__ ei, const float* __restrict__ h,
    const float* __restrict__ s_src, const float* __restrict__ s_dst,
    float* __restrict__ accum)
{
    const int e = blockIdx.x * 4 + (threadIdx.x >> 6);
    if (e >= N_EDGES) return;
    const int lane = threadIdx.x & 63;
    const int src = ei[e];
    const int dst = ei[N_EDGES + e];
    const int head = lane >> 3;

    float v = s_src[src * 8 + head] + s_dst[dst * 8 + head];
    v = (v >= 0.f) ? v : 0.2f * v;          // leaky relu
    float m = v;
    m = fmaxf(m, __shfl_xor(m, 8));
    m = fmaxf(m, __shfl_xor(m, 16));
    m = fmaxf(m, __shfl_xor(m, 32));
    float ex = __expf(v - m);
    float s = ex;
    s += __shfl_xor(s, 8);
    s += __shfl_xor(s, 16);
    s += __shfl_xor(s, 32);
    const float alpha = ex / s;

    const float hv = h[(size_t)dst * 64 + lane];
    atomicAdd(&accum[(size_t)src * 64 + lane], alpha * hv);
}

// ---------------------------------------------------------------------------
// K3: epilogue — residual + LayerNorm + L2 normalize.  One wave per node.
// ---------------------------------------------------------------------------
__global__ __launch_bounds__(256) void k_epilogue(
    const float* __restrict__ accum, const float* __restrict__ x,
    const float* __restrict__ ln_scale, const float* __restrict__ ln_bias,
    float* __restrict__ out)
{
    const int i = blockIdx.x * 4 + (threadIdx.x >> 6);
    if (i >= N_NODES) return;
    const int lane = threadIdx.x & 63;

    float v = accum[(size_t)i * 64 + lane] + x[(size_t)i * 64 + lane];
    float s = v;
    #pragma unroll
    for (int off = 1; off < 64; off <<= 1) s += __shfl_xor(s, off);
    const float mu = s * (1.f / 64.f);
    const float d = v - mu;
    float vs = d * d;
    #pragma unroll
    for (int off = 1; off < 64; off <<= 1) vs += __shfl_xor(vs, off);
    const float var = vs * (1.f / 64.f);
    float y = d * rsqrtf(var + LN_EPS) * ln_scale[lane] + ln_bias[lane];
    float ss = y * y;
    #pragma unroll
    for (int off = 1; off < 64; off <<= 1) ss += __shfl_xor(ss, off);
    const float norm = sqrtf(ss);
    out[(size_t)i * 64 + lane] = y / fmaxf(norm, NORM_EPS);
}

// ---------------------------------------------------------------------------
extern "C" void kernel_launch(void* const* d_in, const int* in_sizes, int n_in,
                              void* d_out, int out_size, void* d_ws, size_t ws_size,
                              hipStream_t stream)
{
    const float* x        = (const float*)d_in[0];
    const int*   ei       = (const int*)d_in[1];
    const float* W        = (const float*)d_in[2];
    const float* b        = (const float*)d_in[3];
    const float* a        = (const float*)d_in[4];
    const float* ln_scale = (const float*)d_in[5];
    const float* ln_bias  = (const float*)d_in[6];
    float* out = (float*)d_out;

    char* ws = (char*)d_ws;
    float* accum = (float*)ws;                                   // N*64 f32
    float* h     = (float*)(ws + (size_t)N_NODES * 64 * 4);      // N*64 f32
    float* s_src = (float*)(ws + (size_t)N_NODES * 64 * 4 * 2);  // N*8 f32
    float* s_dst = s_src + (size_t)N_NODES * 8;                  // N*8 f32

    // ws is re-poisoned to 0xAA before every timed launch -> must zero accum.
    hipMemsetAsync(accum, 0, (size_t)N_NODES * 64 * 4, stream);

    k_gemm    <<<(N_NODES + 15) / 16, 256, 0, stream>>>(x, W, b, a, h, s_src, s_dst);
    k_edge    <<<(N_EDGES + 3) / 4,  256, 0, stream>>>(ei, h, s_src, s_dst, accum);
    k_epilogue<<<(N_NODES + 3) / 4,  256, 0, stream>>>(accum, x, ln_scale, ln_bias, out);
}